// Round 4
// baseline (181.245 us; speedup 1.0000x reference)
//
#include <hip/hip_runtime.h>
#include <hip/hip_cooperative_groups.h>

namespace cg = cooperative_groups;

// QuantumKernelMethod: out[i][j] = |tr(Q_i M_j)|
// Q_i = phi phi^T (phi = V(a_i)|0>), M_j = V(b_j) Z0 V(b_j)^dag = I - 2P,
// P = sum_{p: wire0bit=1} w_p w_p^dag (8 basis sims per y).
// Hermitian pack (K=256): S[k][l] = diag | sqrt2*Re (k<l) | sqrt2*Im mirror (k>l);
// dot(S_Q, S_M) = tr(QM) exactly. out = |Q(1024x256) * M(1024x256)^T|.
//
// Round-4 structure: ONE cooperative kernel, 256 blocks x 512 threads
// (1 block/CU, co-resident). Block b:
//   phase1: 36 sims on wave 0 (32 M-basis sims for cols 4b..4b+3, lanes 0-31;
//           4 Q sims for rows 4b..4b+3, lanes 32-35) -> W/Phi in LDS;
//           assembly: 64 M rows (wave 0) + 64 rank-1 Q rows (wave 1) -> ws.
//   grid.sync() with agent fences (threadfence = wbl2/inv: ws crosses XCD L2s,
//           and ws lines are re-poisoned each iteration -> must invalidate).
//   phase2: 64x64 out tile, 8 waves (each 32x16, 16 MFMA), K=256 from ws.
// Removes the second launch + inter-kernel drain; phase1 latency ~2us on all
// 256 CUs (was ~5us on 34). Harness floor: 256MiB ws poison ~41us + resets.

#define NA 1024
#define NB 1024
#define KD 256
#define RT2 1.41421356237f

typedef __attribute__((ext_vector_type(8))) short bf16x8;
typedef __attribute__((ext_vector_type(4))) float f32x4;

__device__ __forceinline__ unsigned short f2bf(float x) {
    union { float f; unsigned u; } v; v.f = x;
    unsigned r = v.u + 0x7fffu + ((v.u >> 16) & 1u);  // RNE
    return (unsigned short)(r >> 16);
}

__device__ __forceinline__ uint4 pack8(const float* f) {
    uint4 u;
    u.x = (unsigned)f2bf(f[0]) | ((unsigned)f2bf(f[1]) << 16);
    u.y = (unsigned)f2bf(f[2]) | ((unsigned)f2bf(f[3]) << 16);
    u.z = (unsigned)f2bf(f[4]) | ((unsigned)f2bf(f[5]) << 16);
    u.w = (unsigned)f2bf(f[6]) | ((unsigned)f2bf(f[7]) << 16);
    return u;
}

// State: 16 complex amps, flat index = b0*8 + b1*4 + b2*2 + b3 (wire w -> bit 3-w)
__device__ __forceinline__ void ry_gate(float* sr, float* si, int w, float t) {
    float s, c; __sincosf(0.5f * t, &s, &c);
    int st = 8 >> w;
    #pragma unroll
    for (int b = 0; b < 16; ++b) {
        if (b & st) continue;
        int j = b | st;
        float r0 = sr[b], i0 = si[b], r1 = sr[j], i1 = si[j];
        sr[b] = c * r0 - s * r1;  si[b] = c * i0 - s * i1;
        sr[j] = s * r0 + c * r1;  si[j] = s * i0 + c * i1;
    }
}

__device__ __forceinline__ void rx_gate(float* sr, float* si, int w, float t) {
    float s, c; __sincosf(0.5f * t, &s, &c);
    int st = 8 >> w;
    #pragma unroll
    for (int b = 0; b < 16; ++b) {
        if (b & st) continue;
        int j = b | st;
        float r0 = sr[b], i0 = si[b], r1 = sr[j], i1 = si[j];
        sr[b] = c * r0 + s * i1;  si[b] = c * i0 - s * r1;
        sr[j] = c * r1 + s * i0;  si[j] = c * i1 - s * r0;
    }
}

__device__ __forceinline__ void rz_gate(float* sr, float* si, int w, float t) {
    float s, c; __sincosf(0.5f * t, &s, &c);
    int st = 8 >> w;
    #pragma unroll
    for (int b = 0; b < 16; ++b) {
        if (b & st) continue;
        int j = b | st;
        float r0 = sr[b], i0 = si[b], r1 = sr[j], i1 = si[j];
        sr[b] = c * r0 + s * i0;  si[b] = c * i0 - s * r0;
        sr[j] = c * r1 - s * i1;  si[j] = c * i1 + s * r1;
    }
}

__device__ __forceinline__ void cnot_gate(float* sr, float* si, int cw, int tw) {
    int cs = 8 >> cw, ts = 8 >> tw;
    #pragma unroll
    for (int b = 0; b < 16; ++b) {
        if ((b & cs) && !(b & ts)) {
            int j = b | ts;
            float tr = sr[b]; sr[b] = sr[j]; sr[j] = tr;
            float ti = si[b]; si[b] = si[j]; si[j] = ti;
        }
    }
}

__device__ __forceinline__ void ansatz(float* sr, float* si, const float* vec, const float* P) {
    #pragma unroll
    for (int q = 0; q < 4; ++q) ry_gate(sr, si, q, vec[q]);
    #pragma unroll
    for (int l = 0; l < 2; ++l) {
        #pragma unroll
        for (int q = 0; q < 4; ++q) {
            rx_gate(sr, si, q, P[l * 12 + q * 3 + 0]);
            ry_gate(sr, si, q, P[l * 12 + q * 3 + 1]);
            rz_gate(sr, si, q, P[l * 12 + q * 3 + 2]);
        }
        cnot_gate(sr, si, 0, 1);
        cnot_gate(sr, si, 1, 2);
        cnot_gate(sr, si, 2, 3);
        cnot_gate(sr, si, 3, 0);
    }
}

__global__ __launch_bounds__(512, 2) void qkm_mono(
    const float* __restrict__ a, const float* __restrict__ b,
    const float* __restrict__ params,
    unsigned short* __restrict__ Qg, unsigned short* __restrict__ Mg,
    float* __restrict__ out) {

    // W: [y_loc][p][17] split re/im. Banks of (136y+17p+l): 8y+17p+l mod 32,
    // all-distinct over (y,p) for fixed l -> conflict-free writes; assembly
    // reads are 4-address x 16-lane broadcasts, also conflict-free.
    __shared__ float Wtr[4 * 136];
    __shared__ float Wti[4 * 136];
    __shared__ float Phr[4 * 17];
    __shared__ float Phi_[4 * 17];

    const int tid = threadIdx.x;
    const int blk = blockIdx.x;

    // ---- Phase 1a: 36 sims, all on wave 0 ----
    if (tid < 36) {
        float P[24];
        #pragma unroll
        for (int j = 0; j < 24; ++j) P[j] = params[j];
        int init; const float* src;
        if (tid < 32) { init = 8 + (tid & 7); src = b + (size_t)(blk * 4 + (tid >> 3)) * 4; }
        else          { init = 0;             src = a + (size_t)(blk * 4 + (tid - 32)) * 4; }
        float sr[16], si[16];
        #pragma unroll
        for (int k = 0; k < 16; ++k) { sr[k] = (k == init) ? 1.f : 0.f; si[k] = 0.f; }
        float vec[4];
        #pragma unroll
        for (int q = 0; q < 4; ++q) vec[q] = src[q];
        ansatz(sr, si, vec, P);
        if (tid < 32) {
            float* wr = Wtr + (tid >> 3) * 136 + (tid & 7) * 17;
            float* wi = Wti + (tid >> 3) * 136 + (tid & 7) * 17;
            #pragma unroll
            for (int l = 0; l < 16; ++l) { wr[l] = sr[l]; wi[l] = si[l]; }
        } else {
            float* qr = Phr + (tid - 32) * 17;
            float* qi = Phi_ + (tid - 32) * 17;
            #pragma unroll
            for (int l = 0; l < 16; ++l) { qr[l] = sr[l]; qi[l] = si[l]; }
        }
    }
    __syncthreads();

    // ---- Phase 1b: assembly. Wave 0: 64 M rows; wave 1: 64 rank-1 Q rows ----
    if (tid < 64) {
        const int yl = tid >> 4, k = tid & 15;
        const float* wyr = Wtr + yl * 136;
        const float* wyi = Wti + yl * 136;
        float re[16], im[16];
        #pragma unroll
        for (int l = 0; l < 16; ++l) { re[l] = 0.f; im[l] = 0.f; }
        #pragma unroll
        for (int p2 = 0; p2 < 8; ++p2) {
            const float* br  = wyr + p2 * 17;
            const float* bi_ = wyi + p2 * 17;
            float ar = br[k], ai = bi_[k];     // runtime-k: <=2-way, free
            #pragma unroll
            for (int l = 0; l < 16; ++l) {
                float xr = br[l], xi = bi_[l];
                re[l] += ar * xr + ai * xi;    // Re P_{k,l}
                im[l] += xi * ar - xr * ai;    // Im P_{l,k}
            }
        }
        float row[16];
        #pragma unroll
        for (int l = 0; l < 16; ++l) {
            float off = (l < k) ? im[l] : re[l];
            row[l] = (l == k) ? (1.f - 2.f * re[l]) : (-2.f * RT2 * off);
        }
        uint4* d = (uint4*)Mg + (size_t)(blk * 4 + yl) * 32 + k * 2;
        d[0] = pack8(row); d[1] = pack8(row + 8);
    } else if (tid < 128) {
        const int t2 = tid - 64, il = t2 >> 4, k = t2 & 15;
        const float* pr = Phr + il * 17;
        const float* pi = Phi_ + il * 17;
        float rk = pr[k], ik = pi[k];
        float row[16];
        #pragma unroll
        for (int l = 0; l < 16; ++l) {
            float xr = pr[l], xi = pi[l];
            row[l] = (l < k)  ? RT2 * (xi * rk - xr * ik)
                   : (l == k) ? (rk * rk + ik * ik)
                   :            RT2 * (rk * xr + ik * xi);
        }
        uint4* d = (uint4*)Qg + (size_t)(blk * 4 + il) * 32 + k * 2;
        d[0] = pack8(row); d[1] = pack8(row + 8);
    }

    // ---- Grid barrier: S must be globally visible across XCD L2s.
    // release: waitcnt + buffer_wbl2 (flush writer L2); after sync,
    // acquire: buffer_inv (drop stale/poisoned lines in reader L2). ----
    __threadfence();
    cg::this_grid().sync();
    __threadfence();

    // ---- Phase 2: 64x64 tile, 8 waves (2x4), each 32x16, K=256 ----
    const int wave = tid >> 6, lane = tid & 63;
    const int xcd = blk & 7, slot = blk >> 3;    // XCD swizzle (bijective, 256 blocks)
    const int bi = xcd * 2 + (slot >> 4);
    const int bj = slot & 15;
    const int wi = wave >> 2, wj = wave & 3;
    const int row0 = bi * 64 + wi * 32;
    const int col0 = bj * 64 + wj * 16;
    const int m16 = lane & 15, quad = lane >> 4;

    const unsigned short* q0 = Qg + (size_t)(row0 + m16) * KD + quad * 8;
    const unsigned short* q1 = q0 + 16 * KD;
    const unsigned short* m0 = Mg + (size_t)(col0 + m16) * KD + quad * 8;

    f32x4 a0 = {0.f, 0.f, 0.f, 0.f}, a1 = {0.f, 0.f, 0.f, 0.f};
    #pragma unroll
    for (int kk = 0; kk < 8; ++kk) {
        bf16x8 qa = *(const bf16x8*)(q0 + kk * 32);
        bf16x8 qb = *(const bf16x8*)(q1 + kk * 32);
        bf16x8 ma = *(const bf16x8*)(m0 + kk * 32);
        a0 = __builtin_amdgcn_mfma_f32_16x16x32_bf16(qa, ma, a0, 0, 0, 0);
        a1 = __builtin_amdgcn_mfma_f32_16x16x32_bf16(qb, ma, a1, 0, 0, 0);
    }
    // C/D layout: col = lane&15, row = quad*4 + r  [HW-verified]
    #pragma unroll
    for (int r = 0; r < 4; ++r) {
        int orow = row0 + quad * 4 + r;
        out[orow * NB + col0 + m16]        = fabsf(a0[r]);
        out[(orow + 16) * NB + col0 + m16] = fabsf(a1[r]);
    }
}

extern "C" void kernel_launch(void* const* d_in, const int* in_sizes, int n_in,
                              void* d_out, int out_size, void* d_ws, size_t ws_size,
                              hipStream_t stream) {
    const float* a = (const float*)d_in[0];       // 1024 x 4
    const float* b = (const float*)d_in[1];       // 1024 x 4
    const float* params = (const float*)d_in[2];  // 2 x 4 x 3
    float* out = (float*)d_out;                   // 1024 x 1024

    unsigned short* Q = (unsigned short*)d_ws;    // NA x 256 bf16
    unsigned short* M = Q + (size_t)NA * KD;      // NB x 256 bf16

    void* args[] = { (void*)&a, (void*)&b, (void*)&params,
                     (void*)&Q, (void*)&M, (void*)&out };
    hipLaunchCooperativeKernel((const void*)qkm_mono, dim3(256), dim3(512),
                               args, 0, stream);
}

// Round 5
// 72.114 us; speedup vs baseline: 2.5133x; 2.5133x over previous
//
#include <hip/hip_runtime.h>

// QuantumKernelMethod: out[i][j] = |tr(Q_i M_j)|
// Q_i = phi phi^T (phi = V(a_i)|0>), M_j = V(b_j) Z0 V(b_j)^dag = I - 2P,
// P = sum_{p: wire0bit=1} w_p w_p^dag (8 basis sims per y).
// Hermitian pack (K=256): S[k][l] = diag | sqrt2*Re (k<l) | sqrt2*Im mirror (k>l);
// dot(S_Q, S_M) = tr(QM) exactly. out = |Q(1024x256) * M(1024x256)^T|.
//
// Round-5: two kernels (coop grid.sync measured ~100us -> dead; fusion =
// 16x redundant sims -> dead). Phase1 reshaped for latency:
//  - M: 64 blocks x 128 thr. 16 y/block; 128 sims = exactly 1/thread (2
//    waves, no idle pass). W in LDS [y][p][17] split f32: writes/k-reads
//    <=2-way (free), l-reads vectorize to ds_read_b128 8-addr broadcasts.
//    Assembly 2 rows/thread: ~80 LDS insts vs round-0's 544 scalar.
//  - Q: 8 blocks x 128 thr, 1 sim/thread, rank-1 rows from registers.
// Phase2: 256 blocks x 512 thr (8 waves x 32x16/wave, 2x the waves of
// round-0 for L2 load latency hiding), K=256 bf16 MFMA from ws.
// Harness floor ~52us (unconditional 256MiB ws poison ~41us + resets).

#define NA 1024
#define NB 1024
#define KD 256
#define RT2 1.41421356237f

typedef __attribute__((ext_vector_type(8))) short bf16x8;
typedef __attribute__((ext_vector_type(4))) float f32x4;

__device__ __forceinline__ unsigned short f2bf(float x) {
    union { float f; unsigned u; } v; v.f = x;
    unsigned r = v.u + 0x7fffu + ((v.u >> 16) & 1u);  // RNE
    return (unsigned short)(r >> 16);
}

__device__ __forceinline__ uint4 pack8(const float* f) {
    uint4 u;
    u.x = (unsigned)f2bf(f[0]) | ((unsigned)f2bf(f[1]) << 16);
    u.y = (unsigned)f2bf(f[2]) | ((unsigned)f2bf(f[3]) << 16);
    u.z = (unsigned)f2bf(f[4]) | ((unsigned)f2bf(f[5]) << 16);
    u.w = (unsigned)f2bf(f[6]) | ((unsigned)f2bf(f[7]) << 16);
    return u;
}

// State: 16 complex amps, flat index = b0*8 + b1*4 + b2*2 + b3 (wire w -> bit 3-w)
__device__ __forceinline__ void ry_gate(float* sr, float* si, int w, float t) {
    float s, c; __sincosf(0.5f * t, &s, &c);
    int st = 8 >> w;
    #pragma unroll
    for (int b = 0; b < 16; ++b) {
        if (b & st) continue;
        int j = b | st;
        float r0 = sr[b], i0 = si[b], r1 = sr[j], i1 = si[j];
        sr[b] = c * r0 - s * r1;  si[b] = c * i0 - s * i1;
        sr[j] = s * r0 + c * r1;  si[j] = s * i0 + c * i1;
    }
}

__device__ __forceinline__ void rx_gate(float* sr, float* si, int w, float t) {
    float s, c; __sincosf(0.5f * t, &s, &c);
    int st = 8 >> w;
    #pragma unroll
    for (int b = 0; b < 16; ++b) {
        if (b & st) continue;
        int j = b | st;
        float r0 = sr[b], i0 = si[b], r1 = sr[j], i1 = si[j];
        sr[b] = c * r0 + s * i1;  si[b] = c * i0 - s * r1;
        sr[j] = c * r1 + s * i0;  si[j] = c * i1 - s * r0;
    }
}

__device__ __forceinline__ void rz_gate(float* sr, float* si, int w, float t) {
    float s, c; __sincosf(0.5f * t, &s, &c);
    int st = 8 >> w;
    #pragma unroll
    for (int b = 0; b < 16; ++b) {
        if (b & st) continue;
        int j = b | st;
        float r0 = sr[b], i0 = si[b], r1 = sr[j], i1 = si[j];
        sr[b] = c * r0 + s * i0;  si[b] = c * i0 - s * r0;
        sr[j] = c * r1 - s * i1;  si[j] = c * i1 + s * r1;
    }
}

__device__ __forceinline__ void cnot_gate(float* sr, float* si, int cw, int tw) {
    int cs = 8 >> cw, ts = 8 >> tw;
    #pragma unroll
    for (int b = 0; b < 16; ++b) {
        if ((b & cs) && !(b & ts)) {
            int j = b | ts;
            float tr = sr[b]; sr[b] = sr[j]; sr[j] = tr;
            float ti = si[b]; si[b] = si[j]; si[j] = ti;
        }
    }
}

__device__ __forceinline__ void ansatz(float* sr, float* si, const float* vec, const float* P) {
    #pragma unroll
    for (int q = 0; q < 4; ++q) ry_gate(sr, si, q, vec[q]);
    #pragma unroll
    for (int l = 0; l < 2; ++l) {
        #pragma unroll
        for (int q = 0; q < 4; ++q) {
            rx_gate(sr, si, q, P[l * 12 + q * 3 + 0]);
            ry_gate(sr, si, q, P[l * 12 + q * 3 + 1]);
            rz_gate(sr, si, q, P[l * 12 + q * 3 + 2]);
        }
        cnot_gate(sr, si, 0, 1);
        cnot_gate(sr, si, 1, 2);
        cnot_gate(sr, si, 2, 3);
        cnot_gate(sr, si, 3, 0);
    }
}

__global__ __launch_bounds__(128, 1) void qkm_phase1(
    const float* __restrict__ a, const float* __restrict__ b,
    const float* __restrict__ params,
    uint4* __restrict__ Qv, uint4* __restrict__ Mv) {

    float P[24];
    #pragma unroll
    for (int j = 0; j < 24; ++j) P[j] = params[j];
    const int tid = threadIdx.x;
    const int blk = blockIdx.x;

    if (blk < 64) {
        // ---- M-part: 16 y/block, W[y][p][17] split f32 in LDS ----
        __shared__ float Wtr[16 * 136];
        __shared__ float Wti[16 * 136];
        const int col0 = blk << 4;

        {
            const int yl = tid >> 3, p2 = tid & 7;   // 1 sim per thread
            float sr[16], si[16];
            #pragma unroll
            for (int k = 0; k < 16; ++k) { sr[k] = (k == 8 + p2) ? 1.f : 0.f; si[k] = 0.f; }
            float vec[4];
            #pragma unroll
            for (int q = 0; q < 4; ++q) vec[q] = b[(size_t)(col0 + yl) * 4 + q];
            ansatz(sr, si, vec, P);
            float* wr = Wtr + yl * 136 + p2 * 17;
            float* wi = Wti + yl * 136 + p2 * 17;
            #pragma unroll
            for (int l = 0; l < 16; ++l) { wr[l] = sr[l]; wi[l] = si[l]; }
        }
        __syncthreads();

        // Assembly: rows 2*tid, 2*tid+1  (yl = tid>>3, k = 2*(tid&7)+rr)
        const int yl = tid >> 3, k0 = (tid & 7) << 1;
        const float* wyr = Wtr + yl * 136;
        const float* wyi = Wti + yl * 136;
        #pragma unroll
        for (int rr = 0; rr < 2; ++rr) {
            const int k = k0 + rr;
            float re[16], im[16];
            #pragma unroll
            for (int l = 0; l < 16; ++l) { re[l] = 0.f; im[l] = 0.f; }
            #pragma unroll
            for (int p2 = 0; p2 < 8; ++p2) {
                const float* br  = wyr + p2 * 17;
                const float* bi_ = wyi + p2 * 17;
                float ar = br[k], ai = bi_[k];     // runtime-k: <=2-way, free
                #pragma unroll
                for (int l = 0; l < 16; ++l) {
                    float xr = br[l], xi = bi_[l]; // b128 broadcasts, conflict-free
                    re[l] += ar * xr + ai * xi;    // Re P_{k,l}
                    im[l] += xi * ar - xr * ai;    // Im P_{l,k}
                }
            }
            float row[16];
            #pragma unroll
            for (int l = 0; l < 16; ++l) {
                float off = (l < k) ? im[l] : re[l];
                row[l] = (l == k) ? (1.f - 2.f * re[l]) : (-2.f * RT2 * off);
            }
            uint4* d = Mv + (size_t)(col0 + yl) * 32 + k * 2;
            d[0] = pack8(row); d[1] = pack8(row + 8);
        }
    } else {
        // ---- Q-part: blocks 64..71; 1 statevector sim per thread ----
        const int i = ((blk - 64) << 7) + tid;
        float sr[16], si[16];
        #pragma unroll
        for (int k = 0; k < 16; ++k) { sr[k] = (k == 0) ? 1.f : 0.f; si[k] = 0.f; }
        float vec[4];
        #pragma unroll
        for (int q = 0; q < 4; ++q) vec[q] = a[(size_t)i * 4 + q];
        ansatz(sr, si, vec, P);
        // Q = phi phi^dag: Re Q_kl = rk*rl + ik*il; Im Q_lk = il*rk - rl*ik
        #pragma unroll
        for (int k = 0; k < 16; ++k) {
            float rk = sr[k], ik = si[k];
            float row[16];
            #pragma unroll
            for (int l = 0; l < 16; ++l) {
                if (l < k)       row[l] = RT2 * (si[l] * rk - sr[l] * ik);
                else if (l == k) row[l] = rk * rk + ik * ik;
                else             row[l] = RT2 * (rk * sr[l] + ik * si[l]);
            }
            uint4* d = Qv + (size_t)i * 32 + k * 2;
            d[0] = pack8(row); d[1] = pack8(row + 8);
        }
    }
}

// Phase 2: out = |Q * M^T|, bf16 MFMA, K=256. 64x64 tile/block, 8 waves
// (2x4), each wave 32x16 (16 MFMA). XCD swizzle: xcd=blk&7 owns a row band.
__global__ __launch_bounds__(512, 2) void qkm_phase2(
    const unsigned short* __restrict__ Q, const unsigned short* __restrict__ M,
    float* __restrict__ out) {
    const int wave = threadIdx.x >> 6, lane = threadIdx.x & 63;
    const int blk = blockIdx.x;
    const int xcd = blk & 7, slot = blk >> 3;    // bijective over 256 blocks
    const int bi = xcd * 2 + (slot >> 4);        // [0,16)
    const int bj = slot & 15;                    // [0,16)
    const int wi = wave >> 2, wj = wave & 3;
    const int row0 = bi * 64 + wi * 32;
    const int col0 = bj * 64 + wj * 16;
    const int m16 = lane & 15, quad = lane >> 4;

    const unsigned short* q0 = Q + (size_t)(row0 + m16) * KD + quad * 8;
    const unsigned short* q1 = q0 + 16 * KD;
    const unsigned short* m0 = M + (size_t)(col0 + m16) * KD + quad * 8;

    f32x4 a0 = {0.f, 0.f, 0.f, 0.f}, a1 = {0.f, 0.f, 0.f, 0.f};
    #pragma unroll
    for (int kk = 0; kk < 8; ++kk) {
        bf16x8 qa = *(const bf16x8*)(q0 + kk * 32);
        bf16x8 qb = *(const bf16x8*)(q1 + kk * 32);
        bf16x8 ma = *(const bf16x8*)(m0 + kk * 32);
        a0 = __builtin_amdgcn_mfma_f32_16x16x32_bf16(qa, ma, a0, 0, 0, 0);
        a1 = __builtin_amdgcn_mfma_f32_16x16x32_bf16(qb, ma, a1, 0, 0, 0);
    }
    // C/D layout: col = lane&15, row = quad*4 + r  [HW-verified]
    #pragma unroll
    for (int r = 0; r < 4; ++r) {
        int orow = row0 + quad * 4 + r;
        out[orow * NB + col0 + m16]        = fabsf(a0[r]);
        out[(orow + 16) * NB + col0 + m16] = fabsf(a1[r]);
    }
}

extern "C" void kernel_launch(void* const* d_in, const int* in_sizes, int n_in,
                              void* d_out, int out_size, void* d_ws, size_t ws_size,
                              hipStream_t stream) {
    const float* a = (const float*)d_in[0];       // 1024 x 4
    const float* b = (const float*)d_in[1];       // 1024 x 4
    const float* params = (const float*)d_in[2];  // 2 x 4 x 3
    float* out = (float*)d_out;                   // 1024 x 1024

    unsigned short* Q = (unsigned short*)d_ws;    // NA x 256 bf16
    unsigned short* M = Q + (size_t)NA * KD;      // NB x 256 bf16

    qkm_phase1<<<72, 128, 0, stream>>>(a, b, params, (uint4*)Q, (uint4*)M);
    qkm_phase2<<<256, 512, 0, stream>>>(Q, M, out);
}

// Round 6
// 69.676 us; speedup vs baseline: 2.6013x; 1.0350x over previous
//
#include <hip/hip_runtime.h>

// QuantumKernelMethod: out[i][j] = |tr(Q_i M_j)|
// Q_i = phi phi^T (phi = V(a_i)|0>), M_j = V(b_j) Z0 V(b_j)^dag = I - 2P,
// P = sum_{p: wire0bit=1} w_p w_p^dag (8 basis sims per y).
// Hermitian pack (K=256): S[k][l] = diag | sqrt2*Re (k<l) | sqrt2*Im mirror (k>l);
// dot(S_Q, S_M) = tr(QM) exactly. out = |Q(1024x256) * M(1024x256)^T|.
//
// Round-6: best-of-session consolidation.
//  - Phase1 = round-5 shape (72 blocks x 128 thr): M = 64 blocks, 16 y each,
//    128 sims = exactly 1/thread; W in LDS [y][p][17] split f32 (writes /
//    runtime-k reads <=2-way = free; l-reads vectorize to ds_read_b128
//    broadcasts). Assembly 2 rows/thread, ~80 LDS insts (vs 544 scalar in
//    round-0). Q = 8 blocks, 1 sim/thread, rank-1 rows from registers.
//  - Phase2 = round-0 shape (256 blocks x 256 thr, 4 waves 2x2, each wave
//    32x32 = 2x2 frags): max operand reuse (each bf16x8 load feeds 2 MFMAs),
//    best measured total (70.4).
// Refuted this session: fusion (16x redundant sims, +10us), coop grid.sync
// (~100us barrier), wide phase1 (34x512: serialized passes). Harness floor
// ~65us: unconditional 256MiB ws poison (~40us @84% HBM peak = fill's own
// roofline) + out reset + tiny-dispatch forest + graph replay.

#define NA 1024
#define NB 1024
#define KD 256
#define RT2 1.41421356237f

typedef __attribute__((ext_vector_type(8))) short bf16x8;
typedef __attribute__((ext_vector_type(4))) float f32x4;

__device__ __forceinline__ unsigned short f2bf(float x) {
    union { float f; unsigned u; } v; v.f = x;
    unsigned r = v.u + 0x7fffu + ((v.u >> 16) & 1u);  // RNE
    return (unsigned short)(r >> 16);
}

__device__ __forceinline__ uint4 pack8(const float* f) {
    uint4 u;
    u.x = (unsigned)f2bf(f[0]) | ((unsigned)f2bf(f[1]) << 16);
    u.y = (unsigned)f2bf(f[2]) | ((unsigned)f2bf(f[3]) << 16);
    u.z = (unsigned)f2bf(f[4]) | ((unsigned)f2bf(f[5]) << 16);
    u.w = (unsigned)f2bf(f[6]) | ((unsigned)f2bf(f[7]) << 16);
    return u;
}

// State: 16 complex amps, flat index = b0*8 + b1*4 + b2*2 + b3 (wire w -> bit 3-w)
__device__ __forceinline__ void ry_gate(float* sr, float* si, int w, float t) {
    float s, c; __sincosf(0.5f * t, &s, &c);
    int st = 8 >> w;
    #pragma unroll
    for (int b = 0; b < 16; ++b) {
        if (b & st) continue;
        int j = b | st;
        float r0 = sr[b], i0 = si[b], r1 = sr[j], i1 = si[j];
        sr[b] = c * r0 - s * r1;  si[b] = c * i0 - s * i1;
        sr[j] = s * r0 + c * r1;  si[j] = s * i0 + c * i1;
    }
}

__device__ __forceinline__ void rx_gate(float* sr, float* si, int w, float t) {
    float s, c; __sincosf(0.5f * t, &s, &c);
    int st = 8 >> w;
    #pragma unroll
    for (int b = 0; b < 16; ++b) {
        if (b & st) continue;
        int j = b | st;
        float r0 = sr[b], i0 = si[b], r1 = sr[j], i1 = si[j];
        sr[b] = c * r0 + s * i1;  si[b] = c * i0 - s * r1;
        sr[j] = c * r1 + s * i0;  si[j] = c * i1 - s * r0;
    }
}

__device__ __forceinline__ void rz_gate(float* sr, float* si, int w, float t) {
    float s, c; __sincosf(0.5f * t, &s, &c);
    int st = 8 >> w;
    #pragma unroll
    for (int b = 0; b < 16; ++b) {
        if (b & st) continue;
        int j = b | st;
        float r0 = sr[b], i0 = si[b], r1 = sr[j], i1 = si[j];
        sr[b] = c * r0 + s * i0;  si[b] = c * i0 - s * r0;
        sr[j] = c * r1 - s * i1;  si[j] = c * i1 + s * r1;
    }
}

__device__ __forceinline__ void cnot_gate(float* sr, float* si, int cw, int tw) {
    int cs = 8 >> cw, ts = 8 >> tw;
    #pragma unroll
    for (int b = 0; b < 16; ++b) {
        if ((b & cs) && !(b & ts)) {
            int j = b | ts;
            float tr = sr[b]; sr[b] = sr[j]; sr[j] = tr;
            float ti = si[b]; si[b] = si[j]; si[j] = ti;
        }
    }
}

__device__ __forceinline__ void ansatz(float* sr, float* si, const float* vec, const float* P) {
    #pragma unroll
    for (int q = 0; q < 4; ++q) ry_gate(sr, si, q, vec[q]);
    #pragma unroll
    for (int l = 0; l < 2; ++l) {
        #pragma unroll
        for (int q = 0; q < 4; ++q) {
            rx_gate(sr, si, q, P[l * 12 + q * 3 + 0]);
            ry_gate(sr, si, q, P[l * 12 + q * 3 + 1]);
            rz_gate(sr, si, q, P[l * 12 + q * 3 + 2]);
        }
        cnot_gate(sr, si, 0, 1);
        cnot_gate(sr, si, 1, 2);
        cnot_gate(sr, si, 2, 3);
        cnot_gate(sr, si, 3, 0);
    }
}

__global__ __launch_bounds__(128, 1) void qkm_phase1(
    const float* __restrict__ a, const float* __restrict__ b,
    const float* __restrict__ params,
    uint4* __restrict__ Qv, uint4* __restrict__ Mv) {

    float P[24];
    #pragma unroll
    for (int j = 0; j < 24; ++j) P[j] = params[j];
    const int tid = threadIdx.x;
    const int blk = blockIdx.x;

    if (blk < 64) {
        // ---- M-part: 16 y/block, W[y][p][17] split f32 in LDS ----
        __shared__ float Wtr[16 * 136];
        __shared__ float Wti[16 * 136];
        const int col0 = blk << 4;

        {
            const int yl = tid >> 3, p2 = tid & 7;   // 1 sim per thread
            float sr[16], si[16];
            #pragma unroll
            for (int k = 0; k < 16; ++k) { sr[k] = (k == 8 + p2) ? 1.f : 0.f; si[k] = 0.f; }
            float vec[4];
            #pragma unroll
            for (int q = 0; q < 4; ++q) vec[q] = b[(size_t)(col0 + yl) * 4 + q];
            ansatz(sr, si, vec, P);
            float* wr = Wtr + yl * 136 + p2 * 17;
            float* wi = Wti + yl * 136 + p2 * 17;
            #pragma unroll
            for (int l = 0; l < 16; ++l) { wr[l] = sr[l]; wi[l] = si[l]; }
        }
        __syncthreads();

        // Assembly: rows 2*(tid&7), +1 of column yl = tid>>3
        const int yl = tid >> 3, k0 = (tid & 7) << 1;
        const float* wyr = Wtr + yl * 136;
        const float* wyi = Wti + yl * 136;
        #pragma unroll
        for (int rr = 0; rr < 2; ++rr) {
            const int k = k0 + rr;
            float re[16], im[16];
            #pragma unroll
            for (int l = 0; l < 16; ++l) { re[l] = 0.f; im[l] = 0.f; }
            #pragma unroll
            for (int p2 = 0; p2 < 8; ++p2) {
                const float* br  = wyr + p2 * 17;
                const float* bi_ = wyi + p2 * 17;
                float ar = br[k], ai = bi_[k];     // runtime-k: <=2-way, free
                #pragma unroll
                for (int l = 0; l < 16; ++l) {
                    float xr = br[l], xi = bi_[l]; // b128 broadcasts, conflict-free
                    re[l] += ar * xr + ai * xi;    // Re P_{k,l}
                    im[l] += xi * ar - xr * ai;    // Im P_{l,k}
                }
            }
            float row[16];
            #pragma unroll
            for (int l = 0; l < 16; ++l) {
                float off = (l < k) ? im[l] : re[l];
                row[l] = (l == k) ? (1.f - 2.f * re[l]) : (-2.f * RT2 * off);
            }
            uint4* d = Mv + (size_t)(col0 + yl) * 32 + k * 2;
            d[0] = pack8(row); d[1] = pack8(row + 8);
        }
    } else {
        // ---- Q-part: blocks 64..71; 1 statevector sim per thread ----
        const int i = ((blk - 64) << 7) + tid;
        float sr[16], si[16];
        #pragma unroll
        for (int k = 0; k < 16; ++k) { sr[k] = (k == 0) ? 1.f : 0.f; si[k] = 0.f; }
        float vec[4];
        #pragma unroll
        for (int q = 0; q < 4; ++q) vec[q] = a[(size_t)i * 4 + q];
        ansatz(sr, si, vec, P);
        // Q = phi phi^dag: Re Q_kl = rk*rl + ik*il; Im Q_lk = il*rk - rl*ik
        #pragma unroll
        for (int k = 0; k < 16; ++k) {
            float rk = sr[k], ik = si[k];
            float row[16];
            #pragma unroll
            for (int l = 0; l < 16; ++l) {
                if (l < k)       row[l] = RT2 * (si[l] * rk - sr[l] * ik);
                else if (l == k) row[l] = rk * rk + ik * ik;
                else             row[l] = RT2 * (rk * sr[l] + ik * si[l]);
            }
            uint4* d = Qv + (size_t)i * 32 + k * 2;
            d[0] = pack8(row); d[1] = pack8(row + 8);
        }
    }
}

// Phase 2 (round-0 shape, best measured): out = |Q * M^T|, bf16 MFMA, K=256.
// 64x64 tile/block, 4 waves 2x2, each wave 32x32 = 2x2 fragments (each
// operand load feeds 2 MFMAs). XCD swizzle: xcd=blk&7 owns a Q-row band.
__global__ __launch_bounds__(256) void qkm_phase2(
    const unsigned short* __restrict__ Q, const unsigned short* __restrict__ M,
    float* __restrict__ out) {
    int wave = threadIdx.x >> 6;
    int lane = threadIdx.x & 63;
    int blk = blockIdx.x;
    int xcd = blk & 7;
    int slot = blk >> 3;                 // [0,32)
    int bi = xcd * 2 + (slot >> 4);      // [0,16)
    int bj = slot & 15;                  // [0,16)
    int wi = wave >> 1, wj = wave & 1;
    int row0 = bi * 64 + wi * 32;
    int col0 = bj * 64 + wj * 32;
    int m16 = lane & 15;
    int quad = lane >> 4;

    const unsigned short* q0 = Q + (size_t)(row0 + m16) * KD + quad * 8;
    const unsigned short* q1 = q0 + 16 * KD;
    const unsigned short* m0 = M + (size_t)(col0 + m16) * KD + quad * 8;
    const unsigned short* m1 = m0 + 16 * KD;

    f32x4 a00 = {0.f,0.f,0.f,0.f}, a01 = {0.f,0.f,0.f,0.f};
    f32x4 a10 = {0.f,0.f,0.f,0.f}, a11 = {0.f,0.f,0.f,0.f};
    #pragma unroll
    for (int kk = 0; kk < 8; ++kk) {
        bf16x8 qa = *(const bf16x8*)(q0 + kk * 32);
        bf16x8 qb = *(const bf16x8*)(q1 + kk * 32);
        bf16x8 ma = *(const bf16x8*)(m0 + kk * 32);
        bf16x8 mb = *(const bf16x8*)(m1 + kk * 32);
        a00 = __builtin_amdgcn_mfma_f32_16x16x32_bf16(qa, ma, a00, 0, 0, 0);
        a01 = __builtin_amdgcn_mfma_f32_16x16x32_bf16(qa, mb, a01, 0, 0, 0);
        a10 = __builtin_amdgcn_mfma_f32_16x16x32_bf16(qb, ma, a10, 0, 0, 0);
        a11 = __builtin_amdgcn_mfma_f32_16x16x32_bf16(qb, mb, a11, 0, 0, 0);
    }
    // C/D layout: col = lane&15, row = quad*4 + r  [HW-verified]
    #pragma unroll
    for (int r = 0; r < 4; ++r) {
        int r0o = row0 + quad * 4 + r;
        int r1o = r0o + 16;
        out[r0o * NB + col0 + m16]      = fabsf(a00[r]);
        out[r0o * NB + col0 + 16 + m16] = fabsf(a01[r]);
        out[r1o * NB + col0 + m16]      = fabsf(a10[r]);
        out[r1o * NB + col0 + 16 + m16] = fabsf(a11[r]);
    }
}

extern "C" void kernel_launch(void* const* d_in, const int* in_sizes, int n_in,
                              void* d_out, int out_size, void* d_ws, size_t ws_size,
                              hipStream_t stream) {
    const float* a = (const float*)d_in[0];       // 1024 x 4
    const float* b = (const float*)d_in[1];       // 1024 x 4
    const float* params = (const float*)d_in[2];  // 2 x 4 x 3
    float* out = (float*)d_out;                   // 1024 x 1024

    unsigned short* Q = (unsigned short*)d_ws;    // NA x 256 bf16
    unsigned short* M = Q + (size_t)NA * KD;      // NB x 256 bf16

    qkm_phase1<<<72, 128, 0, stream>>>(a, b, params, (uint4*)Q, (uint4*)M);
    qkm_phase2<<<256, 256, 0, stream>>>(Q, M, out);
}